// Round 1
// baseline (7078.185 us; speedup 1.0000x reference)
//
#include <hip/hip_runtime.h>

#define BB 512
#define TT 2048
#define II 8
#define HH 128
#define OO 96

__device__ __forceinline__ float fast_rcp(float x) { return __builtin_amdgcn_rcpf(x); }
__device__ __forceinline__ float sigmoid_fast(float x) {
    return fast_rcp(1.0f + __expf(-x));
}
__device__ __forceinline__ float tanh_fast(float x) {
    // 1 - 2/(1+exp(2x)); stable at both tails (exp->inf gives 1, exp->0 gives -1)
    return 1.0f - 2.0f * fast_rcp(1.0f + __expf(2.0f * x));
}

// Block: 512 threads = 128 j * 4 q. Each block owns 2 batch rows, runs full T scan.
// Thread (j,q): holds w_hh[{j,128+j,256+j}][32q:32q+32] in 96 VGPRs (weight-stationary).
// h lives in LDS, double-buffered; one barrier per step.
__global__ __launch_bounds__(512, 2) void gru_kernel(
    const float* __restrict__ x,     // [B, T, I]
    const float* __restrict__ w_ih,  // [3H, I]
    const float* __restrict__ w_hh,  // [3H, H]
    const float* __restrict__ b_ih,  // [3H]
    const float* __restrict__ b_hh,  // [3H]
    const float* __restrict__ fc_w,  // [O, H]
    const float* __restrict__ fc_b,  // [O]
    float* __restrict__ out)         // [B, O]
{
    __shared__ __align__(16) float hbuf[2][2][HH];

    const int tid = threadIdx.x;
    const int j  = tid >> 2;   // 0..127
    const int q  = tid & 3;    // k-slice
    const int kb = q * 32;
    const int b0 = blockIdx.x * 2;

    // ---- weight-stationary w_hh slices (96 VGPRs) ----
    float wr[32], wz[32], wn[32];
    {
        const float4* pr = (const float4*)(w_hh + (0 * HH + j) * HH + kb);
        const float4* pz = (const float4*)(w_hh + (1 * HH + j) * HH + kb);
        const float4* pn = (const float4*)(w_hh + (2 * HH + j) * HH + kb);
#pragma unroll
        for (int v = 0; v < 8; ++v) {
            float4 a = pr[v], b = pz[v], c = pn[v];
            wr[4 * v + 0] = a.x; wr[4 * v + 1] = a.y; wr[4 * v + 2] = a.z; wr[4 * v + 3] = a.w;
            wz[4 * v + 0] = b.x; wz[4 * v + 1] = b.y; wz[4 * v + 2] = b.z; wz[4 * v + 3] = b.w;
            wn[4 * v + 0] = c.x; wn[4 * v + 1] = c.y; wn[4 * v + 2] = c.z; wn[4 * v + 3] = c.w;
        }
    }

    // ---- per-lane gx weights + bias injection ----
    // lane q computes the input-projection for gate q (q=0:r, q=1:z, q=3:n-gx, q=2: b_hh_n only)
    float wx[8];
    float bias_inj;
    {
        int grow;
        if (q == 0)      { grow = j;        bias_inj = b_ih[j] + b_hh[j]; }
        else if (q == 1) { grow = 128 + j;  bias_inj = b_ih[128 + j] + b_hh[128 + j]; }
        else if (q == 2) { grow = -1;       bias_inj = b_hh[256 + j]; }   // gh_n bias (inside r*(.))
        else             { grow = 256 + j;  bias_inj = b_ih[256 + j]; }   // gx_n bias (outside)
#pragma unroll
        for (int i = 0; i < II; ++i)
            wx[i] = (grow < 0) ? 0.0f : w_ih[grow * II + i];
    }

    // ---- init h = 0 ----
    if (tid < 256) hbuf[0][tid >> 7][tid & 127] = 0.0f;
    float hreg0 = 0.0f, hreg1 = 0.0f;  // this thread's h[b][j] copy
    __syncthreads();

    const float* xrow0 = x + (size_t)(b0 + 0) * TT * II;
    const float* xrow1 = x + (size_t)(b0 + 1) * TT * II;

    int cur = 0;
    for (int t = 0; t < TT; ++t) {
        // x for this step (32B per row, L1-broadcast across the block)
        const float4 xa0 = *(const float4*)(xrow0 + t * II);
        const float4 xb0 = *(const float4*)(xrow0 + t * II + 4);
        const float4 xa1 = *(const float4*)(xrow1 + t * II);
        const float4 xb1 = *(const float4*)(xrow1 + t * II + 4);

        // ---- gh partials: 192 FMAs against LDS h slices ----
        float ar0 = 0.f, az0 = 0.f, an0 = 0.f;
        float ar1 = 0.f, az1 = 0.f, an1 = 0.f;
        const float4* h0p = (const float4*)(&hbuf[cur][0][kb]);
        const float4* h1p = (const float4*)(&hbuf[cur][1][kb]);
#pragma unroll
        for (int v = 0; v < 8; ++v) {
            float4 h0 = h0p[v];
            float4 h1 = h1p[v];
            ar0 = fmaf(wr[4 * v + 0], h0.x, ar0); ar0 = fmaf(wr[4 * v + 1], h0.y, ar0);
            ar0 = fmaf(wr[4 * v + 2], h0.z, ar0); ar0 = fmaf(wr[4 * v + 3], h0.w, ar0);
            az0 = fmaf(wz[4 * v + 0], h0.x, az0); az0 = fmaf(wz[4 * v + 1], h0.y, az0);
            az0 = fmaf(wz[4 * v + 2], h0.z, az0); az0 = fmaf(wz[4 * v + 3], h0.w, az0);
            an0 = fmaf(wn[4 * v + 0], h0.x, an0); an0 = fmaf(wn[4 * v + 1], h0.y, an0);
            an0 = fmaf(wn[4 * v + 2], h0.z, an0); an0 = fmaf(wn[4 * v + 3], h0.w, an0);
            ar1 = fmaf(wr[4 * v + 0], h1.x, ar1); ar1 = fmaf(wr[4 * v + 1], h1.y, ar1);
            ar1 = fmaf(wr[4 * v + 2], h1.z, ar1); ar1 = fmaf(wr[4 * v + 3], h1.w, ar1);
            az1 = fmaf(wz[4 * v + 0], h1.x, az1); az1 = fmaf(wz[4 * v + 1], h1.y, az1);
            az1 = fmaf(wz[4 * v + 2], h1.z, az1); az1 = fmaf(wz[4 * v + 3], h1.w, az1);
            an1 = fmaf(wn[4 * v + 0], h1.x, an1); an1 = fmaf(wn[4 * v + 1], h1.y, an1);
            an1 = fmaf(wn[4 * v + 2], h1.z, an1); an1 = fmaf(wn[4 * v + 3], h1.w, an1);
        }

        // ---- input projection for this lane's gate (8 FMAs per batch row) ----
        float gx0 = bias_inj, gx1 = bias_inj;
        gx0 = fmaf(wx[0], xa0.x, gx0); gx0 = fmaf(wx[1], xa0.y, gx0);
        gx0 = fmaf(wx[2], xa0.z, gx0); gx0 = fmaf(wx[3], xa0.w, gx0);
        gx0 = fmaf(wx[4], xb0.x, gx0); gx0 = fmaf(wx[5], xb0.y, gx0);
        gx0 = fmaf(wx[6], xb0.z, gx0); gx0 = fmaf(wx[7], xb0.w, gx0);
        gx1 = fmaf(wx[0], xa1.x, gx1); gx1 = fmaf(wx[1], xa1.y, gx1);
        gx1 = fmaf(wx[2], xa1.z, gx1); gx1 = fmaf(wx[3], xa1.w, gx1);
        gx1 = fmaf(wx[4], xb1.x, gx1); gx1 = fmaf(wx[5], xb1.y, gx1);
        gx1 = fmaf(wx[6], xb1.z, gx1); gx1 = fmaf(wx[7], xb1.w, gx1);

        // inject into this lane's designated accumulator
        float ap0 = 0.f, ap1 = 0.f;
        if (q == 0)      { ar0 += gx0; ar1 += gx1; }
        else if (q == 1) { az0 += gx0; az1 += gx1; }
        else if (q == 2) { an0 += gx0; an1 += gx1; }
        else             { ap0 = gx0;  ap1 = gx1; }

        // ---- quad butterfly reduction over q (all 4 lanes end with full sums) ----
#define QRED(v) v += __shfl_xor(v, 1); v += __shfl_xor(v, 2);
        QRED(ar0) QRED(az0) QRED(an0) QRED(ap0)
        QRED(ar1) QRED(az1) QRED(an1) QRED(ap1)
#undef QRED

        // ---- activations (redundant on all 4 q-lanes; no divergence) ----
        // r = sig(gx_r + gh_r), z = sig(gx_z + gh_z), n = tanh(gx_n + r*(gh_n + b_hh_n))
        float r0 = sigmoid_fast(ar0);
        float z0 = sigmoid_fast(az0);
        float n0 = tanh_fast(fmaf(r0, an0, ap0));
        float hn0 = fmaf(z0, hreg0 - n0, n0);  // (1-z)n + z h
        float r1 = sigmoid_fast(ar1);
        float z1 = sigmoid_fast(az1);
        float n1 = tanh_fast(fmaf(r1, an1, ap1));
        float hn1 = fmaf(z1, hreg1 - n1, n1);
        hreg0 = hn0; hreg1 = hn1;

        int nxt = cur ^ 1;
        if (q == 0) { hbuf[nxt][0][j] = hn0; hbuf[nxt][1][j] = hn1; }
        __syncthreads();
        cur = nxt;
    }

    // ---- epilogue FC: out[b,o] = h . fc_w[o] + fc_b[o] ----
    if (tid < 2 * OO) {
        const int bb = (tid >= OO) ? 1 : 0;
        const int o  = tid - OO * bb;
        const float4* hf = (const float4*)(&hbuf[cur][bb][0]);
        const float4* wp = (const float4*)(fc_w + o * HH);
        float acc = fc_b[o];
#pragma unroll 8
        for (int v = 0; v < HH / 4; ++v) {
            float4 w4 = wp[v];
            float4 h4 = hf[v];
            acc = fmaf(w4.x, h4.x, acc); acc = fmaf(w4.y, h4.y, acc);
            acc = fmaf(w4.z, h4.z, acc); acc = fmaf(w4.w, h4.w, acc);
        }
        out[(size_t)(b0 + bb) * OO + o] = acc;
    }
}

extern "C" void kernel_launch(void* const* d_in, const int* in_sizes, int n_in,
                              void* d_out, int out_size, void* d_ws, size_t ws_size,
                              hipStream_t stream) {
    const float* x    = (const float*)d_in[0];
    const float* w_ih = (const float*)d_in[1];
    const float* w_hh = (const float*)d_in[2];
    const float* b_ih = (const float*)d_in[3];
    const float* b_hh = (const float*)d_in[4];
    const float* fc_w = (const float*)d_in[5];
    const float* fc_b = (const float*)d_in[6];
    float* out = (float*)d_out;

    gru_kernel<<<BB / 2, 512, 0, stream>>>(x, w_ih, w_hh, b_ih, b_hh, fc_w, fc_b, out);
}

// Round 2
// 2498.078 us; speedup vs baseline: 2.8335x; 2.8335x over previous
//
#include <hip/hip_runtime.h>

#define BB 512
#define TT 2048
#define II 8
#define HH 128
#define OO 96

typedef float f32x2 __attribute__((ext_vector_type(2)));

__device__ __forceinline__ float fast_rcp(float x) { return __builtin_amdgcn_rcpf(x); }
__device__ __forceinline__ float sigmoid_fast(float x) { return fast_rcp(1.0f + __expf(-x)); }
__device__ __forceinline__ float tanh_fast(float x) {
    // 1 - 2/(1+exp(2x)); stable at both tails
    return 1.0f - 2.0f * fast_rcp(1.0f + __expf(2.0f * x));
}

// quad (4-lane) butterfly sum via DPP quad_perm — VALU pipe, no LDS traffic.
template<int CTRL>
__device__ __forceinline__ float dpp_xor_add(float v) {
    int p = __builtin_amdgcn_update_dpp(0, __builtin_bit_cast(int, v), CTRL, 0xF, 0xF, true);
    return v + __builtin_bit_cast(float, p);
}
__device__ __forceinline__ float quad_reduce(float v) {
    v = dpp_xor_add<0xB1>(v);   // xor 1: [1,0,3,2]
    v = dpp_xor_add<0x4E>(v);   // xor 2: [2,3,0,1]
    return v;
}

// 512 threads = 128 j x 4 q. Block owns 2 batch rows, full T scan.
// Conflict fix: thread q visits k-chunks in rotated order c=(u+q)&7 so the 4
// q-lanes of a quad hit 4 distinct bank groups per ds_read_b128.
__global__ __launch_bounds__(512, 2) void gru_kernel(
    const float* __restrict__ x,     // [B, T, I]
    const float* __restrict__ w_ih,  // [3H, I]
    const float* __restrict__ w_hh,  // [3H, H]
    const float* __restrict__ b_ih,  // [3H]
    const float* __restrict__ b_hh,  // [3H]
    const float* __restrict__ fc_w,  // [O, H]
    const float* __restrict__ fc_b,  // [O]
    float* __restrict__ out)         // [B, O]
{
    __shared__ __align__(16) float hbuf[2][2][HH];  // [buf][row][h]: buf stride 1024B, row stride 512B

    const int tid = threadIdx.x;
    const int j = tid >> 2;   // 0..127
    const int q = tid & 3;    // k-slice
    const int b0 = blockIdx.x * 2;

    // ---- weight-stationary w_hh, stored PRE-ROTATED: slot u = k-chunk c=(q+u)&7 ----
    f32x2 wr2[16], wz2[16], wn2[16];   // 96 VGPRs total
#pragma unroll
    for (int u = 0; u < 8; ++u) {
        const int c = (q + u) & 7;
        const int kk = q * 32 + c * 4;
        float4 a = *(const float4*)(w_hh + (0 * HH + j) * HH + kk);
        float4 b = *(const float4*)(w_hh + (1 * HH + j) * HH + kk);
        float4 g = *(const float4*)(w_hh + (2 * HH + j) * HH + kk);
        f32x2 t;
        t.x = a.x; t.y = a.y; wr2[2*u] = t;   t.x = a.z; t.y = a.w; wr2[2*u+1] = t;
        t.x = b.x; t.y = b.y; wz2[2*u] = t;   t.x = b.z; t.y = b.w; wz2[2*u+1] = t;
        t.x = g.x; t.y = g.y; wn2[2*u] = t;   t.x = g.z; t.y = g.w; wn2[2*u+1] = t;
    }

    // ---- per-lane gx role (q=0:r, q=1:z, q=2: b_hh_n only, q=3: gx_n) ----
    f32x2 wx2[4];
    float bias_inj;
    {
        int grow;
        if (q == 0)      { grow = j;       bias_inj = b_ih[j] + b_hh[j]; }
        else if (q == 1) { grow = 128 + j; bias_inj = b_ih[128 + j] + b_hh[128 + j]; }
        else if (q == 2) { grow = -1;      bias_inj = b_hh[256 + j]; }   // gh_n bias (inside r*(.))
        else             { grow = 256 + j; bias_inj = b_ih[256 + j]; }   // gx_n bias (outside)
#pragma unroll
        for (int i = 0; i < 4; ++i) {
            f32x2 t;
            t.x = (grow < 0) ? 0.f : w_ih[grow * II + 2 * i];
            t.y = (grow < 0) ? 0.f : w_ih[grow * II + 2 * i + 1];
            wx2[i] = t;
        }
    }

    // ---- rotated LDS read pointers (row0/buf0 base; buf/row folded as imm offsets) ----
    const char* rp[8];
    {
        const char* base = (const char*)&hbuf[0][0][0];
#pragma unroll
        for (int u = 0; u < 8; ++u)
            rp[u] = base + q * 128 + (((q + u) & 7) << 4);
    }
    char* wp = (char*)&hbuf[0][0][0] + j * 4;

    if (tid < 256) hbuf[0][tid >> 7][tid & 127] = 0.0f;
    float hreg0 = 0.f, hreg1 = 0.f;
    __syncthreads();

    const float* xr0 = x + (size_t)(b0 + 0) * TT * II;
    const float* xr1 = x + (size_t)(b0 + 1) * TT * II;

    // preload x for t=0,1 (both rows)
    float4 xe0a = *(const float4*)(xr0 + 0), xe0b = *(const float4*)(xr0 + 4);
    float4 xe1a = *(const float4*)(xr1 + 0), xe1b = *(const float4*)(xr1 + 4);
    float4 xo0a = *(const float4*)(xr0 + 8), xo0b = *(const float4*)(xr0 + 12);
    float4 xo1a = *(const float4*)(xr1 + 8), xo1b = *(const float4*)(xr1 + 12);

#define GRU_STEP(RB, WB, Xa0, Xb0, Xa1, Xb1)                                    \
    {                                                                           \
        f32x2 ar0 = {0.f, 0.f}, az0 = {0.f, 0.f}, an0 = {0.f, 0.f};             \
        f32x2 ar1 = {0.f, 0.f}, az1 = {0.f, 0.f}, an1 = {0.f, 0.f};             \
        _Pragma("unroll")                                                       \
        for (int u = 0; u < 8; ++u) {                                           \
            float4 h0 = *(const float4*)(rp[u] + (RB) * 1024);                  \
            float4 h1 = *(const float4*)(rp[u] + (RB) * 1024 + 512);            \
            f32x2 h0a; h0a.x = h0.x; h0a.y = h0.y;                              \
            f32x2 h0b; h0b.x = h0.z; h0b.y = h0.w;                              \
            f32x2 h1a; h1a.x = h1.x; h1a.y = h1.y;                              \
            f32x2 h1b; h1b.x = h1.z; h1b.y = h1.w;                              \
            ar0 = __builtin_elementwise_fma(wr2[2*u],   h0a, ar0);              \
            ar0 = __builtin_elementwise_fma(wr2[2*u+1], h0b, ar0);              \
            az0 = __builtin_elementwise_fma(wz2[2*u],   h0a, az0);              \
            az0 = __builtin_elementwise_fma(wz2[2*u+1], h0b, az0);              \
            an0 = __builtin_elementwise_fma(wn2[2*u],   h0a, an0);              \
            an0 = __builtin_elementwise_fma(wn2[2*u+1], h0b, an0);              \
            ar1 = __builtin_elementwise_fma(wr2[2*u],   h1a, ar1);              \
            ar1 = __builtin_elementwise_fma(wr2[2*u+1], h1b, ar1);              \
            az1 = __builtin_elementwise_fma(wz2[2*u],   h1a, az1);              \
            az1 = __builtin_elementwise_fma(wz2[2*u+1], h1b, az1);              \
            an1 = __builtin_elementwise_fma(wn2[2*u],   h1a, an1);              \
            an1 = __builtin_elementwise_fma(wn2[2*u+1], h1b, an1);              \
        }                                                                       \
        float sr0 = ar0.x + ar0.y, sz0 = az0.x + az0.y, sn0 = an0.x + an0.y;    \
        float sr1 = ar1.x + ar1.y, sz1 = az1.x + az1.y, sn1 = an1.x + an1.y;    \
        f32x2 g0 = {bias_inj, 0.f}, g1 = {bias_inj, 0.f};                       \
        {                                                                       \
            f32x2 t;                                                            \
            t.x = (Xa0).x; t.y = (Xa0).y; g0 = __builtin_elementwise_fma(wx2[0], t, g0); \
            t.x = (Xa0).z; t.y = (Xa0).w; g0 = __builtin_elementwise_fma(wx2[1], t, g0); \
            t.x = (Xb0).x; t.y = (Xb0).y; g0 = __builtin_elementwise_fma(wx2[2], t, g0); \
            t.x = (Xb0).z; t.y = (Xb0).w; g0 = __builtin_elementwise_fma(wx2[3], t, g0); \
            t.x = (Xa1).x; t.y = (Xa1).y; g1 = __builtin_elementwise_fma(wx2[0], t, g1); \
            t.x = (Xa1).z; t.y = (Xa1).w; g1 = __builtin_elementwise_fma(wx2[1], t, g1); \
            t.x = (Xb1).x; t.y = (Xb1).y; g1 = __builtin_elementwise_fma(wx2[2], t, g1); \
            t.x = (Xb1).z; t.y = (Xb1).w; g1 = __builtin_elementwise_fma(wx2[3], t, g1); \
        }                                                                       \
        float gxa = g0.x + g0.y, gxb = g1.x + g1.y;                             \
        float ap0 = 0.f, ap1 = 0.f;                                             \
        if (q == 0)      { sr0 += gxa; sr1 += gxb; }                            \
        else if (q == 1) { sz0 += gxa; sz1 += gxb; }                            \
        else if (q == 2) { sn0 += gxa; sn1 += gxb; }                            \
        else             { ap0 = gxa;  ap1 = gxb; }                             \
        sr0 = quad_reduce(sr0); sz0 = quad_reduce(sz0);                         \
        sn0 = quad_reduce(sn0); ap0 = quad_reduce(ap0);                         \
        sr1 = quad_reduce(sr1); sz1 = quad_reduce(sz1);                         \
        sn1 = quad_reduce(sn1); ap1 = quad_reduce(ap1);                         \
        float r0 = sigmoid_fast(sr0), z0 = sigmoid_fast(sz0);                   \
        float n0 = tanh_fast(fmaf(r0, sn0, ap0));                               \
        float hn0 = fmaf(z0, hreg0 - n0, n0);                                   \
        float r1 = sigmoid_fast(sr1), z1 = sigmoid_fast(sz1);                   \
        float n1 = tanh_fast(fmaf(r1, sn1, ap1));                               \
        float hn1 = fmaf(z1, hreg1 - n1, n1);                                   \
        hreg0 = hn0; hreg1 = hn1;                                               \
        if (q == 0) {                                                           \
            *(float*)(wp + (WB) * 1024)       = hn0;                            \
            *(float*)(wp + (WB) * 1024 + 512) = hn1;                            \
        }                                                                       \
        __syncthreads();                                                        \
    }

    for (int it = 0; it < TT / 2; ++it) {
        // prefetch x for t = 2it+2, 2it+3 (uniform addresses -> scalar loads; clamped at end)
        const int tn = (2 * it + 2 < TT) ? (2 * it + 2) : 0;
        float4 pe0a = *(const float4*)(xr0 + tn * II),      pe0b = *(const float4*)(xr0 + tn * II + 4);
        float4 pe1a = *(const float4*)(xr1 + tn * II),      pe1b = *(const float4*)(xr1 + tn * II + 4);
        float4 po0a = *(const float4*)(xr0 + tn * II + 8),  po0b = *(const float4*)(xr0 + tn * II + 12);
        float4 po1a = *(const float4*)(xr1 + tn * II + 8),  po1b = *(const float4*)(xr1 + tn * II + 12);

        GRU_STEP(0, 1, xe0a, xe0b, xe1a, xe1b)   // even t: read buf0, write buf1
        GRU_STEP(1, 0, xo0a, xo0b, xo1a, xo1b)   // odd  t: read buf1, write buf0

        xe0a = pe0a; xe0b = pe0b; xe1a = pe1a; xe1b = pe1b;
        xo0a = po0a; xo0b = po0b; xo1a = po1a; xo1b = po1b;
    }
#undef GRU_STEP

    // ---- epilogue FC: final h is in buf 0 ----
    if (tid < 2 * OO) {
        const int bb = (tid >= OO) ? 1 : 0;
        const int o  = tid - OO * bb;
        const float4* hf = (const float4*)(&hbuf[0][bb][0]);
        const float4* wpw = (const float4*)(fc_w + o * HH);
        float acc = fc_b[o];
#pragma unroll 8
        for (int v = 0; v < HH / 4; ++v) {
            float4 w4 = wpw[v];
            float4 h4 = hf[v];
            acc = fmaf(w4.x, h4.x, acc); acc = fmaf(w4.y, h4.y, acc);
            acc = fmaf(w4.z, h4.z, acc); acc = fmaf(w4.w, h4.w, acc);
        }
        out[(size_t)(b0 + bb) * OO + o] = acc;
    }
}

extern "C" void kernel_launch(void* const* d_in, const int* in_sizes, int n_in,
                              void* d_out, int out_size, void* d_ws, size_t ws_size,
                              hipStream_t stream) {
    const float* x    = (const float*)d_in[0];
    const float* w_ih = (const float*)d_in[1];
    const float* w_hh = (const float*)d_in[2];
    const float* b_ih = (const float*)d_in[3];
    const float* b_hh = (const float*)d_in[4];
    const float* fc_w = (const float*)d_in[5];
    const float* fc_b = (const float*)d_in[6];
    float* out = (float*)d_out;

    gru_kernel<<<BB / 2, 512, 0, stream>>>(x, w_ih, w_hh, b_ih, b_hh, fc_w, fc_b, out);
}

// Round 3
// 1158.115 us; speedup vs baseline: 6.1118x; 2.1570x over previous
//
#include <hip/hip_runtime.h>

#define BB 512
#define TT 2048
#define II 8
#define HH 128
#define OO 96

typedef __attribute__((ext_vector_type(8))) short bf16x8;
typedef __attribute__((ext_vector_type(4))) float f32x4;

__device__ __forceinline__ float fast_rcp(float x) { return __builtin_amdgcn_rcpf(x); }
__device__ __forceinline__ float sigmoid_fast(float x) { return fast_rcp(1.0f + __expf(-x)); }
__device__ __forceinline__ float tanh_fast(float x) {
    // 1 - 2/(1+exp(2x)); stable at both tails
    return 1.0f - 2.0f * fast_rcp(1.0f + __expf(2.0f * x));
}
__device__ __forceinline__ unsigned short f2bf(float f) {
    unsigned int u = __builtin_bit_cast(unsigned int, f);
    u += 0x7fffu + ((u >> 16) & 1u);   // RNE
    return (unsigned short)(u >> 16);
}
__device__ __forceinline__ float bf2f(unsigned short h) {
    unsigned int u = ((unsigned int)h) << 16;
    return __builtin_bit_cast(float, u);
}

// Block = 8 waves (512 thr), 2 batch rows, full T scan.
// Wave w owns j-block [16w,16w+16). MFMA 16x16x32 bf16, K_ext=160:
//   A rows: {h_hi(b0), h_hi(b1), h_lo(b0), h_lo(b1)} x k=[h(128) | x(8) | 0pad(24)]
//   gh+gx (b) = C[row b] + C[row b+2]  (bf16 split compensation)
// LDS h-buffer: 2 x 4 planes x 160 bf16 (plane=320B, buf=1280B), double-buffered.
__global__ __launch_bounds__(512, 2) void gru_kernel(
    const float* __restrict__ x,     // [B, T, I]
    const float* __restrict__ w_ih,  // [3H, I]
    const float* __restrict__ w_hh,  // [3H, H]
    const float* __restrict__ b_ih,  // [3H]
    const float* __restrict__ b_hh,  // [3H]
    const float* __restrict__ fc_w,  // [O, H]
    const float* __restrict__ fc_b,  // [O]
    float* __restrict__ out)         // [B, O]
{
    __shared__ __align__(16) char hbuf[2 * 1280];
    __shared__ __align__(16) float hfin[2][HH];

    const int tid = threadIdx.x;
    const int wv  = tid >> 6;
    const int ln  = tid & 63;
    const int col = ln & 15;       // C col = j within tile
    const int g4  = ln >> 4;       // k-subblock of A/B fragment
    const int p   = col & 3;       // A plane: rows 4..15 duplicate 0..3
    const int j   = 16 * wv + col;
    const int b0  = blockIdx.x * 2;

    // ---- B fragments (weights -> bf16, weight-stationary) ----
    // B[k=(ln>>4)*8+i][n=ln&15]: lane loads 8 consecutive k from w_hh row (gate,j)
    auto ldfrag_hh = [&](int grow, int ks) {
        const float* rowp = w_hh + grow * HH + 32 * ks + g4 * 8;
        float4 u = *(const float4*)(rowp);
        float4 v = *(const float4*)(rowp + 4);
        bf16x8 f;
        f[0] = (short)f2bf(u.x); f[1] = (short)f2bf(u.y);
        f[2] = (short)f2bf(u.z); f[3] = (short)f2bf(u.w);
        f[4] = (short)f2bf(v.x); f[5] = (short)f2bf(v.y);
        f[6] = (short)f2bf(v.z); f[7] = (short)f2bf(v.w);
        return f;
    };
    auto ldfrag_ih = [&](int grow) {      // k-step 4: W_ih in k'=0..7, zeros above
        bf16x8 f = {0, 0, 0, 0, 0, 0, 0, 0};
        if (g4 == 0) {
            const float* rowp = w_ih + grow * II;
            float4 u = *(const float4*)(rowp);
            float4 v = *(const float4*)(rowp + 4);
            f[0] = (short)f2bf(u.x); f[1] = (short)f2bf(u.y);
            f[2] = (short)f2bf(u.z); f[3] = (short)f2bf(u.w);
            f[4] = (short)f2bf(v.x); f[5] = (short)f2bf(v.y);
            f[6] = (short)f2bf(v.z); f[7] = (short)f2bf(v.w);
        }
        return f;
    };

    bf16x8 bR[5], bZ[5], bN[4], bX;
#pragma unroll
    for (int ks = 0; ks < 4; ++ks) {
        bR[ks] = ldfrag_hh(j, ks);
        bZ[ks] = ldfrag_hh(HH + j, ks);
        bN[ks] = ldfrag_hh(2 * HH + j, ks);
    }
    bR[4] = ldfrag_ih(j);
    bZ[4] = ldfrag_ih(HH + j);
    bX    = ldfrag_ih(2 * HH + j);

    const float bias_r  = b_ih[j] + b_hh[j];
    const float bias_z  = b_ih[HH + j] + b_hh[HH + j];
    const float bias_nh = b_hh[2 * HH + j];   // inside r*(.)
    const float bias_nx = b_ih[2 * HH + j];   // outside

    // ---- zero LDS (h=0, pads=0 both buffers) ----
    for (int i = tid; i < 640; i += 512) ((int*)hbuf)[i] = 0;
    __syncthreads();

    // ---- x staging: wave 7, lanes 0..15 (lane = 8*b + i) ----
    const float* xr = x + (size_t)(b0 + (ln >> 3)) * TT * II + (ln & 7);
    float xc1 = 0.f, xc2 = 0.f;
    if (wv == 7 && ln < 16) {
        float x0 = xr[0];
        xc1 = xr[II];          // x(t=1)
        xc2 = xr[2 * II];      // x(t=2)
        unsigned short xh = f2bf(x0);
        char* xw = hbuf + ((ln >> 3) * 320) + (128 + (ln & 7)) * 2;  // buf0
        *(unsigned short*)(xw)       = xh;
        *(unsigned short*)(xw + 640) = f2bf(x0 - bf2f(xh));
    }
    __syncthreads();

    const char* abase = hbuf + p * 320 + g4 * 16;
    char* hw = hbuf + j * 2;
    float h0 = 0.f, h1 = 0.f;
    const f32x4 zf = {0.f, 0.f, 0.f, 0.f};

#define STEP(BUF, XVAL)                                                         \
    {                                                                           \
        const char* ab = abase + (BUF) * 1280;                                  \
        bf16x8 a0 = *(const bf16x8*)(ab);                                       \
        bf16x8 a1 = *(const bf16x8*)(ab + 64);                                  \
        bf16x8 a2 = *(const bf16x8*)(ab + 128);                                 \
        bf16x8 a3 = *(const bf16x8*)(ab + 192);                                 \
        bf16x8 a4 = *(const bf16x8*)(ab + 256);                                 \
        f32x4 aR = zf, aZ = zf, aN = zf, aX = zf;                               \
        aR = __builtin_amdgcn_mfma_f32_16x16x32_bf16(a0, bR[0], aR, 0, 0, 0);   \
        aZ = __builtin_amdgcn_mfma_f32_16x16x32_bf16(a0, bZ[0], aZ, 0, 0, 0);   \
        aN = __builtin_amdgcn_mfma_f32_16x16x32_bf16(a0, bN[0], aN, 0, 0, 0);   \
        aR = __builtin_amdgcn_mfma_f32_16x16x32_bf16(a1, bR[1], aR, 0, 0, 0);   \
        aZ = __builtin_amdgcn_mfma_f32_16x16x32_bf16(a1, bZ[1], aZ, 0, 0, 0);   \
        aN = __builtin_amdgcn_mfma_f32_16x16x32_bf16(a1, bN[1], aN, 0, 0, 0);   \
        aR = __builtin_amdgcn_mfma_f32_16x16x32_bf16(a2, bR[2], aR, 0, 0, 0);   \
        aZ = __builtin_amdgcn_mfma_f32_16x16x32_bf16(a2, bZ[2], aZ, 0, 0, 0);   \
        aN = __builtin_amdgcn_mfma_f32_16x16x32_bf16(a2, bN[2], aN, 0, 0, 0);   \
        aR = __builtin_amdgcn_mfma_f32_16x16x32_bf16(a3, bR[3], aR, 0, 0, 0);   \
        aZ = __builtin_amdgcn_mfma_f32_16x16x32_bf16(a3, bZ[3], aZ, 0, 0, 0);   \
        aN = __builtin_amdgcn_mfma_f32_16x16x32_bf16(a3, bN[3], aN, 0, 0, 0);   \
        aR = __builtin_amdgcn_mfma_f32_16x16x32_bf16(a4, bR[4], aR, 0, 0, 0);   \
        aZ = __builtin_amdgcn_mfma_f32_16x16x32_bf16(a4, bZ[4], aZ, 0, 0, 0);   \
        aX = __builtin_amdgcn_mfma_f32_16x16x32_bf16(a4, bX,    aX, 0, 0, 0);   \
        float gr0 = aR[0] + aR[2] + bias_r,  gr1 = aR[1] + aR[3] + bias_r;      \
        float gz0 = aZ[0] + aZ[2] + bias_z,  gz1 = aZ[1] + aZ[3] + bias_z;      \
        float gn0 = aN[0] + aN[2] + bias_nh, gn1 = aN[1] + aN[3] + bias_nh;     \
        float gx0 = aX[0] + aX[2] + bias_nx, gx1 = aX[1] + aX[3] + bias_nx;     \
        float r0 = sigmoid_fast(gr0), r1 = sigmoid_fast(gr1);                   \
        float z0 = sigmoid_fast(gz0), z1 = sigmoid_fast(gz1);                   \
        float n0 = tanh_fast(fmaf(r0, gn0, gx0));                               \
        float n1 = tanh_fast(fmaf(r1, gn1, gx1));                               \
        h0 = fmaf(z0, h0 - n0, n0);                                             \
        h1 = fmaf(z1, h1 - n1, n1);                                             \
        if (ln < 16) {                                                          \
            char* w_ = hw + (1 - (BUF)) * 1280;                                 \
            unsigned short s0 = f2bf(h0), s1 = f2bf(h1);                        \
            *(unsigned short*)(w_)       = s0;                                  \
            *(unsigned short*)(w_ + 320) = s1;                                  \
            *(unsigned short*)(w_ + 640) = f2bf(h0 - bf2f(s0));                 \
            *(unsigned short*)(w_ + 960) = f2bf(h1 - bf2f(s1));                 \
        }                                                                       \
        if (wv == 7 && ln < 16) {                                               \
            unsigned short xh = f2bf(XVAL);                                     \
            char* xw = hbuf + (1 - (BUF)) * 1280 + ((ln >> 3) * 320)            \
                       + (128 + (ln & 7)) * 2;                                  \
            *(unsigned short*)(xw)       = xh;                                  \
            *(unsigned short*)(xw + 640) = f2bf((XVAL) - bf2f(xh));             \
        }                                                                       \
        __syncthreads();                                                        \
    }

    for (int it = 0; it < TT / 2; ++it) {
        float xn1 = 0.f, xn2 = 0.f;
        if (wv == 7 && ln < 16) {                     // prefetch x(t+3), x(t+4)
            int t3 = 2 * it + 3; if (t3 >= TT) t3 = TT - 1;
            int t4 = 2 * it + 4; if (t4 >= TT) t4 = TT - 1;
            xn1 = xr[t3 * II];
            xn2 = xr[t4 * II];
        }
        STEP(0, xc1)    // even t: read buf0, write buf1 (+ stage x(t+1))
        STEP(1, xc2)    // odd  t: read buf1, write buf0
        xc1 = xn1; xc2 = xn2;
    }
#undef STEP

    // ---- epilogue FC on fp32 h ----
    if (ln < 16) { hfin[0][j] = h0; hfin[1][j] = h1; }
    __syncthreads();

    if (tid < 2 * OO) {
        const int bb2 = (tid >= OO) ? 1 : 0;
        const int o   = tid - OO * bb2;
        const float4* hf = (const float4*)(&hfin[bb2][0]);
        const float4* wp = (const float4*)(fc_w + o * HH);
        float acc = fc_b[o];
#pragma unroll 8
        for (int v = 0; v < HH / 4; ++v) {
            float4 w4 = wp[v];
            float4 h4 = hf[v];
            acc = fmaf(w4.x, h4.x, acc); acc = fmaf(w4.y, h4.y, acc);
            acc = fmaf(w4.z, h4.z, acc); acc = fmaf(w4.w, h4.w, acc);
        }
        out[(size_t)(b0 + bb2) * OO + o] = acc;
    }
}

extern "C" void kernel_launch(void* const* d_in, const int* in_sizes, int n_in,
                              void* d_out, int out_size, void* d_ws, size_t ws_size,
                              hipStream_t stream) {
    const float* x    = (const float*)d_in[0];
    const float* w_ih = (const float*)d_in[1];
    const float* w_hh = (const float*)d_in[2];
    const float* b_ih = (const float*)d_in[3];
    const float* b_hh = (const float*)d_in[4];
    const float* fc_w = (const float*)d_in[5];
    const float* fc_b = (const float*)d_in[6];
    float* out = (float*)d_out;

    gru_kernel<<<BB / 2, 512, 0, stream>>>(x, w_ih, w_hh, b_ih, b_hh, fc_w, fc_b, out);
}